// Round 7
// baseline (4235.350 us; speedup 1.0000x reference)
//
#include <hip/hip_runtime.h>

#define TSTEPS  2048
#define DIN     64
#define UNITS   128
#define UNFOLDS 6
#define NT      256

// W=4 waves, UPT=8, P=16. Lane (g=tid>>4, p=tid&15) owns units 8g..8g+7,
// K-chunk [8p,8p+8). 64 FMA/lane into acc[8]; reduce-scatter: xor1+xor2 DPP
// stages (keep-half cndmask) -> 2 values/lane (adjacent units 8g+u0,+u0+1,
// u0 = 4*(p&1)+2*((p>>1)&1)), then ror4+ror8 full cross-quad sum (R5-verified
// trick). Nonlin x2 per lane; p<4 publish ds_write_b64. h layout padded:
// h[u] at word u+4*(u>>3) -> reads at word 12p are 2-way bank alias (free),
// writes conflict-free. LDS-pipe: 4 waves x 2 b128 = ~108 cyc (was 192);
// VALU: 1 wave/SIMD x ~123 instr. Raw s_barrier keeps x prefetch in flight.

template <int CTRL>
__device__ __forceinline__ float dpp_f(float v) {
    return __int_as_float(
        __builtin_amdgcn_mov_dpp(__float_as_int(v), CTRL, 0xF, 0xF, true));
}

__global__ __launch_bounds__(NT) void ltc_kernel(
    const float* __restrict__ x,      // [B,T,DIN]
    const float* __restrict__ kern,   // [DIN,UNITS]
    const float* __restrict__ rk,     // [UNITS,UNITS]
    const float* __restrict__ bias,   // [UNITS]
    const float* __restrict__ tau,    // [UNITS]
    const float* __restrict__ Avec,   // [UNITS]
    const float* __restrict__ okern,  // [UNITS,1]
    const float* __restrict__ obias,  // [1]
    float* __restrict__ out)          // [B,T,1]
{
    const int b    = blockIdx.x;
    const int tid  = threadIdx.x;
    const int p    = tid & 15;      // K-chunk id
    const int g    = tid >> 4;      // unit group: units 8g..8g+7
    const int wid  = tid >> 6;
    const int lane = tid & 63;

    // padded h: h[u] at word u + 4*(u>>3); 16 blocks * 12 words = 192/buf
    __shared__ __align__(16) float hbuf[2][192];
    __shared__ float part[4];

    // resident weights: rk[8p+m][8g+j]  (8x8 = 64 regs)
    float w_[8][8];
    #pragma unroll
    for (int m = 0; m < 8; ++m) {
        const float* row = rk + (size_t)(8 * p + m) * UNITS + 8 * g;
        #pragma unroll
        for (int j = 0; j < 8; ++j) w_[m][j] = row[j];
    }
    // input kernel: kern[4p+m][8g+j]  (4x8 = 32 regs)
    float kk_[4][8];
    #pragma unroll
    for (int m = 0; m < 4; ++m) {
        const float* row = kern + (size_t)(4 * p + m) * UNITS + 8 * g;
        #pragma unroll
        for (int j = 0; j < 8; ++j) kk_[m][j] = row[j];
    }
    float bias_[8];
    #pragma unroll
    for (int j = 0; j < 8; ++j) bias_[j] = (p == 0) ? bias[8 * g + j] : 0.0f;

    // scatter endpoint: this lane ends owning units ua=8g+u0, ub=ua+1
    const int   u0  = ((p & 1) << 2) | (p & 2);
    const int   ua  = 8 * g + u0;
    const float dt  = 1.0f / 6.0f;
    float2 Af = *(const float2*)(Avec + ua);
    float2 Tf = *(const float2*)(tau + ua);
    float2 Of = *(const float2*)(okern + ua);
    const float dtA0 = dt * Af.x, dtA1 = dt * Af.y;
    const float cd0  = 1.0f + dt / Tf.x, cd1 = 1.0f + dt / Tf.y;
    const float cp0  = cd0 + dt, cp1 = cd1 + dt;
    const float ok0  = Of.x, ok1 = Of.y;
    const float ob   = obias[0];
    const int   waddr = 12 * g + u0;        // padded word of unit ua (even)

    float h0 = 0.0f, h1 = 0.0f;
    for (int i = tid; i < 192; i += NT) { hbuf[0][i] = 0.0f; hbuf[1][i] = 0.0f; }

    const float* xb = x + (size_t)b * TSTEPS * DIN;
    float4 xr = *(const float4*)(xb + 4 * p);   // x[b][0][4p..4p+4)
    __syncthreads();

    for (int t = 0; t < TSTEPS; ++t) {
        // input-projection partials for the 8 owned units over x[4p..4p+4)
        float xp[8];
        #pragma unroll
        for (int j = 0; j < 8; ++j) xp[j] = bias_[j];
        {
            float xrf[4] = {xr.x, xr.y, xr.z, xr.w};
            #pragma unroll
            for (int m = 0; m < 4; ++m)
                #pragma unroll
                for (int j = 0; j < 8; ++j)
                    xp[j] = fmaf(xrf[m], kk_[m][j], xp[j]);
        }
        // prefetch next x row (raw barriers leave it in flight)
        int tn = (t + 1 < TSTEPS) ? t + 1 : t;
        float4 xn = *(const float4*)(xb + (size_t)tn * DIN + 4 * p);

        #pragma unroll
        for (int s = 0; s < UNFOLDS; ++s) {
            const float4* hv = (const float4*)&hbuf[s & 1][12 * p];
            float4 ha = hv[0], hc = hv[1];
            float hf[8] = {ha.x, ha.y, ha.z, ha.w, hc.x, hc.y, hc.z, hc.w};

            float acc[8];
            #pragma unroll
            for (int j = 0; j < 8; ++j) acc[j] = xp[j];
            #pragma unroll
            for (int m = 0; m < 8; ++m)
                #pragma unroll
                for (int j = 0; j < 8; ++j)
                    acc[j] = fmaf(hf[m], w_[m][j], acc[j]);

            // ---- reduce-scatter over the 16-lane row ----
            const bool q0 = (p & 1) != 0;
            const bool q1 = (p & 2) != 0;
            float r_[4];
            #pragma unroll
            for (int j = 0; j < 4; ++j) {        // xor1: keep {0..3} / {4..7}
                float mine = q0 ? acc[j + 4] : acc[j];
                float send = q0 ? acc[j] : acc[j + 4];
                r_[j] = mine + dpp_f<0xB1>(send);
            }
            float s0, s1;
            {                                     // xor2: keep pair {0,1}/{2,3}
                float m0 = q1 ? r_[2] : r_[0];
                float e0 = q1 ? r_[0] : r_[2];
                s0 = m0 + dpp_f<0x4E>(e0);
                float m1 = q1 ? r_[3] : r_[1];
                float e1 = q1 ? r_[1] : r_[3];
                s1 = m1 + dpp_f<0x4E>(e1);
            }
            s0 += dpp_f<0x124>(s0);  s0 += dpp_f<0x128>(s0);   // cross-quad sum
            s1 += dpp_f<0x124>(s1);  s1 += dpp_f<0x128>(s1);

            // nonlinearity + semi-implicit Euler, 2 units per lane
            float e0v = __expf(-s0);
            h0 = fmaf(h0, e0v, h0 + dtA0) *
                 __builtin_amdgcn_rcpf(fmaf(cd0, e0v, cp0));
            float e1v = __expf(-s1);
            h1 = fmaf(h1, e1v, h1 + dtA1) *
                 __builtin_amdgcn_rcpf(fmaf(cd1, e1v, cp1));

            if (p < 4) {    // publish both units, one b64, conflict-free
                float2 st; st.x = h0; st.y = h1;
                *(float2*)&hbuf[(s & 1) ^ 1][waddr] = st;
            }

            if (s == UNFOLDS - 1) {
                // head: q over all 128 units; pairs within quad via dpp,
                // rows via shfl16, halves via shfl32
                float q = fmaf(h0, ok0, h1 * ok1);
                q += dpp_f<0xB1>(q);
                q += dpp_f<0x4E>(q);
                q += __shfl_xor(q, 16);
                q += __shfl_xor(q, 32);
                if (lane == 0) part[wid] = q;
            }

            asm volatile("s_waitcnt lgkmcnt(0)" ::: "memory");
            __builtin_amdgcn_sched_barrier(0);
            __builtin_amdgcn_s_barrier();
            __builtin_amdgcn_sched_barrier(0);
        }

        if (tid == 0)
            out[(size_t)b * TSTEPS + t] = part[0] + part[1] + part[2] + part[3] + ob;
        xr = xn;
    }
}

extern "C" void kernel_launch(void* const* d_in, const int* in_sizes, int n_in,
                              void* d_out, int out_size, void* d_ws, size_t ws_size,
                              hipStream_t stream) {
    const float* x     = (const float*)d_in[0];
    const float* kern  = (const float*)d_in[1];
    const float* rk    = (const float*)d_in[2];
    const float* bias  = (const float*)d_in[3];
    const float* tau   = (const float*)d_in[4];
    const float* Avec  = (const float*)d_in[5];
    const float* okern = (const float*)d_in[6];
    const float* obias = (const float*)d_in[7];
    float* out = (float*)d_out;

    ltc_kernel<<<64, NT, 0, stream>>>(
        x, kern, rk, bias, tau, Avec, okern, obias, out);
}

// Round 8
// 3844.686 us; speedup vs baseline: 1.1016x; 1.1016x over previous
//
#include <hip/hip_runtime.h>

#define TSTEPS  2048
#define DIN     64
#define UNITS   128
#define UNFOLDS 6
#define NT      512

// R5 skeleton (verified): thread (g = tid>>4, p = tid&15) owns units
// {4g..4g+3} x K-chunk [8p,8p+8). Changes:
//  - h exchanged through LDS as f16: chunk = 8 f16 = 16B -> ONE ds_read_b128
//    per lane (was 2). Contiguous [128]-f16 layout: 16 lanes x 4 words cover
//    banks 0..31 twice = 2-way alias (free, m136). Publish = ds_write_b16.
//  - recurrent MACs via v_dot2_f32_f16 (f16*f16 + f32): 16 dot2/lane
//    (was 32 FMA). W resident as f16 K-pairs. x-projection stays fp32.
//  - 16-lane reduce-scatter + nonlinearity + head: identical to R5.

template <int CTRL>
__device__ __forceinline__ float dpp_f(float v) {
    return __int_as_float(
        __builtin_amdgcn_mov_dpp(__float_as_int(v), CTRL, 0xF, 0xF, true));
}

typedef _Float16 h16x2 __attribute__((ext_vector_type(2)));

__device__ __forceinline__ float dot2(h16x2 a, h16x2 b, float c) {
#if __has_builtin(__builtin_amdgcn_fdot2)
    return __builtin_amdgcn_fdot2(a, b, c, false);
#else
    return fmaf((float)a.x, (float)b.x, fmaf((float)a.y, (float)b.y, c));
#endif
}

__global__ __launch_bounds__(NT) void ltc_kernel(
    const float* __restrict__ x,      // [B,T,DIN]
    const float* __restrict__ kern,   // [DIN,UNITS]
    const float* __restrict__ rk,     // [UNITS,UNITS]
    const float* __restrict__ bias,   // [UNITS]
    const float* __restrict__ tau,    // [UNITS]
    const float* __restrict__ Avec,   // [UNITS]
    const float* __restrict__ okern,  // [UNITS,1]
    const float* __restrict__ obias,  // [1]
    float* __restrict__ out)          // [B,T,1]
{
    const int b    = blockIdx.x;
    const int tid  = threadIdx.x;
    const int p    = tid & 15;      // K-chunk id
    const int g    = tid >> 4;      // unit group: units 4g..4g+3
    const int wid  = tid >> 6;
    const int lane = tid & 63;

    __shared__ __align__(16) _Float16 hbuf[2][UNITS];
    __shared__ float part[8];

    // resident recurrent weights as f16 K-pairs:
    // w2_[m][j] = ( rk[8p+2m][4g+j], rk[8p+2m+1][4g+j] )
    h16x2 w2_[4][4];
    #pragma unroll
    for (int m = 0; m < 4; ++m) {
        const float* r0 = rk + (size_t)(8 * p + 2 * m) * UNITS + 4 * g;
        const float* r1 = r0 + UNITS;
        #pragma unroll
        for (int j = 0; j < 4; ++j) {
            h16x2 v; v.x = (_Float16)r0[j]; v.y = (_Float16)r1[j];
            w2_[m][j] = v;
        }
    }
    // input kernel fp32: kern[4p+m][4g+j]
    float kk_[4][4];
    #pragma unroll
    for (int m = 0; m < 4; ++m) {
        float4 v = ((const float4*)(kern + (size_t)(4 * p + m) * UNITS))[g];
        kk_[m][0] = v.x; kk_[m][1] = v.y; kk_[m][2] = v.z; kk_[m][3] = v.w;
    }

    const float dt  = 1.0f / 6.0f;
    const int   sel = ((p & 1) << 1) | ((p >> 1) & 1);  // scatter endpoint
    const int   u_own = 4 * g + sel;
    const float dtA_o  = dt * Avec[u_own];
    const float cden_o = 1.0f + dt / tau[u_own];
    const float cdp_o  = cden_o + dt;
    const float ok_o   = okern[u_own];
    float4 bv = ((const float4*)bias)[g];
    float bias4[4] = {bv.x, bv.y, bv.z, bv.w};
    const float ob = obias[0];

    float h_own = 0.0f;
    if (tid < UNITS) { hbuf[0][tid] = (_Float16)0.f; hbuf[1][tid] = (_Float16)0.f; }

    const float* xb = x + (size_t)b * TSTEPS * DIN;
    float4 xr = *(const float4*)(xb + 4 * p);   // x[b][0][4p..4p+4)
    __syncthreads();

    for (int t = 0; t < TSTEPS; ++t) {
        // input-projection partial (fp32 exact), valid all 6 sub-steps
        float xp[4];
        #pragma unroll
        for (int i = 0; i < 4; ++i) xp[i] = (p == 0) ? bias4[i] : 0.0f;
        {
            float xrf[4] = {xr.x, xr.y, xr.z, xr.w};
            #pragma unroll
            for (int m = 0; m < 4; ++m)
                #pragma unroll
                for (int i = 0; i < 4; ++i)
                    xp[i] = fmaf(xrf[m], kk_[m][i], xp[i]);
        }
        // prefetch next x row (raw barriers keep it in flight)
        int tn = (t + 1 < TSTEPS) ? t + 1 : t;
        float4 xn = *(const float4*)(xb + (size_t)tn * DIN + 4 * p);

        #pragma unroll
        for (int s = 0; s < UNFOLDS; ++s) {
            // one b128: this chunk's 8 f16 h values
            h16x2 hh[4];
            *(uint4*)hh = *(const uint4*)&hbuf[s & 1][8 * p];

            float acc[4] = {xp[0], xp[1], xp[2], xp[3]};
            #pragma unroll
            for (int m = 0; m < 4; ++m)
                #pragma unroll
                for (int j = 0; j < 4; ++j)
                    acc[j] = dot2(hh[m], w2_[m][j], acc[j]);

            // ---- 16-lane reduce-scatter (R5-verified) ----
            const bool b0 = (p & 1) != 0;
            const bool b1 = (p & 2) != 0;
            float a0 = b0 ? acc[2] : acc[0];
            float c0 = b0 ? acc[0] : acc[2];
            float r0 = a0 + dpp_f<0xB1>(c0);
            float a1 = b0 ? acc[3] : acc[1];
            float c1 = b0 ? acc[1] : acc[3];
            float r1 = a1 + dpp_f<0xB1>(c1);
            float a2 = b1 ? r1 : r0;
            float c2 = b1 ? r0 : r1;
            float sv = a2 + dpp_f<0x4E>(c2);
            sv += dpp_f<0x124>(sv);   // row_ror:4
            sv += dpp_f<0x128>(sv);   // row_ror:8

            // gating + semi-implicit Euler update, once per lane
            float e   = __expf(-sv);                  // f = 1/(1+e)
            float num = fmaf(h_own, e, h_own + dtA_o);
            float den = fmaf(cden_o, e, cdp_o);
            h_own = num * __builtin_amdgcn_rcpf(den);

            if (p < 4) hbuf[(s & 1) ^ 1][u_own] = (_Float16)h_own;  // b16 publish

            if (s == UNFOLDS - 1) {
                float q = (p < 4) ? h_own * ok_o : 0.0f;
                q += __shfl_xor(q, 1);
                q += __shfl_xor(q, 2);
                q += __shfl_xor(q, 4);
                q += __shfl_xor(q, 8);
                q += __shfl_xor(q, 16);
                q += __shfl_xor(q, 32);
                if (lane == 0) part[wid] = q;
            }

            asm volatile("s_waitcnt lgkmcnt(0)" ::: "memory");
            __builtin_amdgcn_sched_barrier(0);
            __builtin_amdgcn_s_barrier();
            __builtin_amdgcn_sched_barrier(0);
        }

        if (tid == 0) {
            float r = ob;
            #pragma unroll
            for (int k = 0; k < 8; ++k) r += part[k];
            out[(size_t)b * TSTEPS + t] = r;
        }
        xr = xn;
    }
}

extern "C" void kernel_launch(void* const* d_in, const int* in_sizes, int n_in,
                              void* d_out, int out_size, void* d_ws, size_t ws_size,
                              hipStream_t stream) {
    const float* x     = (const float*)d_in[0];
    const float* kern  = (const float*)d_in[1];
    const float* rk    = (const float*)d_in[2];
    const float* bias  = (const float*)d_in[3];
    const float* tau   = (const float*)d_in[4];
    const float* Avec  = (const float*)d_in[5];
    const float* okern = (const float*)d_in[6];
    const float* obias = (const float*)d_in[7];
    float* out = (float*)d_out;

    ltc_kernel<<<64, NT, 0, stream>>>(
        x, kern, rk, bias, tau, Avec, okern, obias, out);
}